// Round 1
// baseline (391.737 us; speedup 1.0000x reference)
//
#include <hip/hip_runtime.h>

typedef float f4v __attribute__((ext_vector_type(4)));
typedef _Float16 h8 __attribute__((ext_vector_type(8)));
typedef _Float16 h4 __attribute__((ext_vector_type(4)));

// Problem constants
// C=192, NH=8, DH=24, window 6x8x8 -> N=384 tokens, D/H/W = 24/64/64 -> 256 windows
// shift (3,4,4). Spatial stride per channel = 24*64*64 = 98304.

__device__ __forceinline__ float fast_exp2(float x) {
#if __has_builtin(__builtin_amdgcn_exp2f)
    return __builtin_amdgcn_exp2f(x);
#else
    return exp2f(x);
#endif
}
__device__ __forceinline__ float fast_rcp(float x) {
#if __has_builtin(__builtin_amdgcn_rcpf)
    return __builtin_amdgcn_rcpf(x);
#else
    return 1.0f / x;
#endif
}

// ---------------------------------------------------------------------------
// Kernel 1: transpose + roll + window-partition + LayerNorm -> f16 staging
// grid (1536, 3): block = one (d,h) source row-pair, y = tensor (q,k,v)
// ---------------------------------------------------------------------------
__global__ __launch_bounds__(256) void ln_stage_kernel(
    const float* __restrict__ q, const float* __restrict__ k, const float* __restrict__ v,
    const float* __restrict__ nqw, const float* __restrict__ nqb,
    const float* __restrict__ nkw, const float* __restrict__ nkb,
    _Float16* __restrict__ Qs, _Float16* __restrict__ Ks, _Float16* __restrict__ Vs)
{
    const int tid = threadIdx.x;
    const int bid = blockIdx.x;      // d*64 + h
    const int tensor = blockIdx.y;   // 0=q, 1=k, 2=v
    const int d = bid >> 6;
    const int h = bid & 63;

    const float* src = (tensor == 0) ? q : (tensor == 1) ? k : v;
    const float* gam = (tensor == 0) ? nqw : nkw;
    const float* bet = (tensor == 0) ? nqb : nkb;
    _Float16* dst = (tensor == 0) ? Qs : (tensor == 1) ? Ks : Vs;
    // fold softmax scale (1/sqrt(24)) and log2(e) into Q so scores are in exp2 domain
    const float scale = (tensor == 0) ? (0.20412414523193154f * 1.44269504088896340f) : 1.0f;

    __shared__ __attribute__((aligned(16))) float tile[192][64];
    __shared__ float psum[4][64];
    __shared__ float psq[4][64];
    __shared__ float smean[64];
    __shared__ float srstd[64];
    __shared__ float sgam[192];
    __shared__ float sbet[192];

    if (tid < 192) { sgam[tid] = gam[tid]; sbet[tid] = bet[tid]; }

    // coalesced load of 192 channels x 64 w (256B per row)
    {
        const float* base = src + (size_t)d * 4096 + (size_t)h * 64;
        const int c0 = tid >> 4;
        const int col = (tid & 15) << 2;
        #pragma unroll
        for (int r = 0; r < 12; ++r) {
            int c = r * 16 + c0;
            f4v x = *(const f4v*)(base + (size_t)c * 98304 + col);
            *(f4v*)&tile[c][col] = x;
        }
    }
    __syncthreads();

    // per-token (per-w-column) mean / var
    {
        const int wcol = tid & 63;
        const int p = tid >> 6;
        float s = 0.f, ss = 0.f;
        #pragma unroll
        for (int i = 0; i < 48; ++i) {
            float x = tile[p * 48 + i][wcol];
            s += x; ss += x * x;
        }
        psum[p][wcol] = s; psq[p][wcol] = ss;
    }
    __syncthreads();
    if (tid < 64) {
        float S  = psum[0][tid] + psum[1][tid] + psum[2][tid] + psum[3][tid];
        float SS = psq[0][tid] + psq[1][tid] + psq[2][tid] + psq[3][tid];
        float mean = S * (1.0f / 192.0f);
        float var = SS * (1.0f / 192.0f) - mean * mean;
        smean[tid] = mean;
        srstd[tid] = rsqrtf(var + 1e-5f);
    }
    __syncthreads();

    // normalize + write f16 staging at (win, n, c)
    {
        const int wpos = tid >> 2;   // 0..63 source w
        const int p = tid & 3;       // channel quarter
        const float mean = smean[wpos];
        const float rstd = srstd[wpos];
        // rolled coordinates: rolled index i <- source (i + shift) ; i = (src - shift) mod dim
        int d_r = d + 21; if (d_r >= 24) d_r -= 24;
        int h_r = h + 60; if (h_r >= 64) h_r -= 64;
        int w_r = wpos + 60; if (w_r >= 64) w_r -= 64;
        const int wi = d_r / 6, td = d_r - wi * 6;
        const int hi = h_r >> 3, th = h_r & 7;
        const int wj = w_r >> 3, tw = w_r & 7;
        const int win = (wi * 8 + hi) * 8 + wj;
        const int n = (td * 8 + th) * 8 + tw;
        _Float16* out = dst + ((size_t)win * 384 + n) * 192;
        #pragma unroll
        for (int cc = 0; cc < 6; ++cc) {
            const int c = p * 48 + cc * 8;
            h8 hv;
            #pragma unroll
            for (int j = 0; j < 8; ++j) {
                float x = (tile[c + j][wpos] - mean) * rstd * sgam[c + j] + sbet[c + j];
                hv[j] = (_Float16)(x * scale);
            }
            *(h8*)(out + c) = hv;
        }
    }
}

// ---------------------------------------------------------------------------
// Kernel 2: proj_w f32 -> f16
// ---------------------------------------------------------------------------
__global__ __launch_bounds__(256) void wconv_kernel(const float* __restrict__ w,
                                                    _Float16* __restrict__ wb)
{
    int i = blockIdx.x * 256 + threadIdx.x;
    if (i < 192 * 192) wb[i] = (_Float16)w[i];
}

// ---------------------------------------------------------------------------
// Kernel 3: windowed attention, one block per (window, head). 4 waves.
// Swapped QK^T (S^T = mfma(K, Q)) so softmax per q is lane-local + 2 shfl_xor.
// ---------------------------------------------------------------------------
__global__ __launch_bounds__(256) void attn_kernel(
    const _Float16* __restrict__ Qs, const _Float16* __restrict__ Ks,
    const _Float16* __restrict__ Vs, _Float16* __restrict__ AOs)
{
    const int win = blockIdx.x;
    const int head = blockIdx.y;
    const int tid = threadIdx.x;
    const int lane = tid & 63;
    const int wid = tid >> 6;
    const int l15 = lane & 15;
    const int g = lane >> 4;

    __shared__ __attribute__((aligned(16))) _Float16 Kh[384 * 40];   // [token][dh pad40], dh 24..31 zeroed
    __shared__ __attribute__((aligned(16))) _Float16 Vt[32 * 392];   // [dh][token pad392]
    __shared__ __attribute__((aligned(16))) _Float16 P[4][16 * 384]; // per-wave P, XOR-swizzled 16B units
    __shared__ __attribute__((aligned(4)))  unsigned char rid[384];

    const int wi = win >> 6, hi = (win >> 3) & 7, wj = win & 7;
    const bool mixed = (wi == 3) || (hi == 7) || (wj == 7);

    const size_t wbase = (size_t)win * 384 * 192 + head * 24;
    const _Float16* Kw = Ks + wbase;
    const _Float16* Vw = Vs + wbase;
    const _Float16* Qw = Qs + wbase;
    _Float16* AOw = AOs + wbase;

    // ---- stage K (row-major, padded) and V^T, zero K pad, region ids ----
    {
        const h8 z8 = {};
        #pragma unroll
        for (int it = 0; it < 6; ++it) {
            int idx = it * 256 + tid;     // 0..1535
            int ch = idx / 384;           // 0..3
            int n = idx - ch * 384;
            if (ch < 3) {
                h8 kv = *(const h8*)(Kw + (size_t)n * 192 + ch * 8);
                h8 vv = *(const h8*)(Vw + (size_t)n * 192 + ch * 8);
                *(h8*)(Kh + n * 40 + ch * 8) = kv;
                #pragma unroll
                for (int j = 0; j < 8; ++j) Vt[(ch * 8 + j) * 392 + n] = vv[j];
            } else {
                *(h8*)(Kh + n * 40 + 24) = z8;   // zero dh 24..31
            }
        }
        for (int n = tid; n < 384; n += 256) {
            int twn = n & 7, thn = (n >> 3) & 7, tdn = n >> 6;
            int rd = (wi == 3) ? (tdn < 3 ? 1 : 2) : 0;
            int rh = (hi == 7) ? (thn < 4 ? 1 : 2) : 0;
            int rw = (wj == 7) ? (twn < 4 ? 1 : 2) : 0;
            rid[n] = (unsigned char)(rd * 9 + rh * 3 + rw);
        }
    }
    __syncthreads();

    _Float16* Pw = P[wid];

    for (int qt = 0; qt < 6; ++qt) {
        const int q0 = wid * 96 + qt * 16;

        // Q as B-operand: lane holds Q[q0 + l15][8g..8g+7]; dh 24..31 zero
        h8 qf = {};
        if (g < 3) qf = *(const h8*)(Qw + (size_t)(q0 + l15) * 192 + g * 8);

        // S^T[k][q] tiles: 24 independent MFMAs (K-dim = dh in one shot)
        f4v s[24];
        #pragma unroll
        for (int mt = 0; mt < 24; ++mt) {
            h8 kf = *(const h8*)(Kh + (16 * mt + l15) * 40 + g * 8);
            f4v z = {};
            s[mt] = __builtin_amdgcn_mfma_f32_16x16x32_f16(kf, qf, z, 0, 0, 0);
        }
        // lane l holds s for q = q0 + l15, k = 16*mt + 4*g + j

        if (mixed) {
            const unsigned int rq = rid[q0 + l15];
            #pragma unroll
            for (int mt = 0; mt < 24; ++mt) {
                unsigned int r4 = *(const unsigned int*)(rid + 16 * mt + 4 * g);
                #pragma unroll
                for (int j = 0; j < 4; ++j) {
                    if (((r4 >> (8 * j)) & 255u) != rq) s[mt][j] = -1e30f;
                }
            }
        }

        // softmax over k for fixed q: lane-local 96 values + reduce over g-groups
        float m = -3e38f;
        #pragma unroll
        for (int mt = 0; mt < 24; ++mt)
            m = fmaxf(m, fmaxf(fmaxf(s[mt][0], s[mt][1]), fmaxf(s[mt][2], s[mt][3])));
        m = fmaxf(m, __shfl_xor(m, 16));
        m = fmaxf(m, __shfl_xor(m, 32));

        __syncthreads();   // protect previous iteration's P reads (WAR)

        float sum = 0.f;
        #pragma unroll
        for (int mt = 0; mt < 24; ++mt) {
            h4 ph;
            #pragma unroll
            for (int j = 0; j < 4; ++j) {
                float p = fast_exp2(s[mt][j] - m);
                sum += p;
                ph[j] = (_Float16)p;
            }
            // P[q][k] row-major, 16B-unit XOR swizzle by (q&7)
            const int k0 = 16 * mt + 4 * g;
            const int u = (k0 >> 3) ^ (l15 & 7);
            *(h4*)((char*)Pw + l15 * 768 + u * 16 + ((k0 & 7) << 1)) = ph;
        }
        sum += __shfl_xor(sum, 16);
        sum += __shfl_xor(sum, 32);

        __syncthreads();   // P visible to all lanes of the wave (compiler fence + HW)

        // PV: O[q][dh] = P[q][:] * V ; A = P (row-major), B via Vt rows
        f4v o0 = {}, o1 = {};
        #pragma unroll
        for (int kt = 0; kt < 12; ++kt) {
            const int u = (4 * kt + g) ^ (l15 & 7);
            h8 pf = *(const h8*)((const char*)Pw + l15 * 768 + u * 16);
            h8 v0 = *(const h8*)(Vt + l15 * 392 + 32 * kt + 8 * g);
            h8 v1 = *(const h8*)(Vt + (16 + l15) * 392 + 32 * kt + 8 * g);
            o0 = __builtin_amdgcn_mfma_f32_16x16x32_f16(pf, v0, o0, 0, 0, 0);
            o1 = __builtin_amdgcn_mfma_f32_16x16x32_f16(pf, v1, o1, 0, 0, 0);
        }

        // normalize by row-sum and store f16 (dh 0..15 from o0, 16..23 from o1)
        #pragma unroll
        for (int j = 0; j < 4; ++j) {
            float sj = __shfl(sum, 4 * g + j);
            float inv = fast_rcp(sj);
            const size_t row = (size_t)(q0 + 4 * g + j) * 192;
            AOw[row + l15] = (_Float16)(o0[j] * inv);
            if (l15 < 8) AOw[row + 16 + l15] = (_Float16)(o1[j] * inv);
        }
    }
}

// ---------------------------------------------------------------------------
// Kernel 4: projection (X @ W^T + b) + window-reverse + roll-back + transpose
// block = half a window (192 tokens), 4 waves x 48 tokens.
// ---------------------------------------------------------------------------
__global__ __launch_bounds__(256) void proj_kernel(
    const _Float16* __restrict__ AOs, const _Float16* __restrict__ Wb,
    const float* __restrict__ bias, float* __restrict__ out)
{
    const int bid = blockIdx.x;
    const int win = bid >> 1, half = bid & 1;
    const int tid = threadIdx.x;
    const int lane = tid & 63, wid = tid >> 6;
    const int l15 = lane & 15, g = lane >> 4;
    const int wi = win >> 6, hi = (win >> 3) & 7, wj = win & 7;

    __shared__ __attribute__((aligned(16))) float tileT[4][192 * 20];
    float* Tw = tileT[wid];

    for (int mi = 0; mi < 3; ++mi) {
        __syncthreads();   // WAR: previous epilogue reads done before overwrite
        const int tb = half * 192 + wid * 48 + mi * 16;
        f4v acc[12];
        const f4v zz = {};
        #pragma unroll
        for (int n = 0; n < 12; ++n) acc[n] = zz;
        #pragma unroll
        for (int kk = 0; kk < 6; ++kk) {
            h8 af = *(const h8*)(AOs + ((size_t)win * 384 + tb + l15) * 192 + kk * 32 + g * 8);
            #pragma unroll
            for (int n = 0; n < 12; ++n) {
                h8 bf = *(const h8*)(Wb + (size_t)(n * 16 + l15) * 192 + kk * 32 + g * 8);
                acc[n] = __builtin_amdgcn_mfma_f32_16x16x32_f16(af, bf, acc[n], 0, 0, 0);
            }
        }
        // bias + transpose through LDS ([c][token16] pad20 -> conflict-free)
        #pragma unroll
        for (int n = 0; n < 12; ++n) {
            float b = bias[n * 16 + l15];
            f4v vv = acc[n];
            vv[0] += b; vv[1] += b; vv[2] += b; vv[3] += b;
            *(f4v*)(Tw + (n * 16 + l15) * 20 + g * 4) = vv;
        }
        __syncthreads();   // make per-wave tile visible across lanes (compiler fence)

        // each lane owns one token (i = l15), c = rr*4 + g -> 32B-coalesced stores
        const int i = l15;
        const int nn = tb + i;
        const int twn = nn & 7, thn = (nn >> 3) & 7, tdn = nn >> 6;
        int dd = wi * 6 + tdn + 3; if (dd >= 24) dd -= 24;
        int hh = hi * 8 + thn + 4; if (hh >= 64) hh -= 64;
        int ww = wj * 8 + twn + 4; if (ww >= 64) ww -= 64;
        const size_t sp = (size_t)dd * 4096 + hh * 64 + ww;
        #pragma unroll
        for (int rr = 0; rr < 48; ++rr) {
            const int c = rr * 4 + g;
            out[(size_t)c * 98304 + sp] = Tw[c * 20 + i];
        }
    }
}

// ---------------------------------------------------------------------------
extern "C" void kernel_launch(void* const* d_in, const int* in_sizes, int n_in,
                              void* d_out, int out_size, void* d_ws, size_t ws_size,
                              hipStream_t stream) {
    const float* q_map = (const float*)d_in[0];
    const float* k_map = (const float*)d_in[1];
    const float* v_map = (const float*)d_in[2];
    const float* nqw = (const float*)d_in[3];
    const float* nqb = (const float*)d_in[4];
    const float* nkw = (const float*)d_in[5];
    const float* nkb = (const float*)d_in[6];
    const float* pw = (const float*)d_in[7];
    const float* pb = (const float*)d_in[8];
    float* out = (float*)d_out;

    // workspace layout (f16): Qs, Ks, Vs, AOs each 256*384*192; Wb 192*192
    _Float16* ws = (_Float16*)d_ws;
    const size_t BUF = (size_t)256 * 384 * 192;
    _Float16* Qs = ws;
    _Float16* Ks = ws + BUF;
    _Float16* Vs = ws + 2 * BUF;
    _Float16* AOs = ws + 3 * BUF;
    _Float16* Wb = ws + 4 * BUF;   // total ~151 MB

    ln_stage_kernel<<<dim3(1536, 3), 256, 0, stream>>>(q_map, k_map, v_map,
                                                       nqw, nqb, nkw, nkb, Qs, Ks, Vs);
    wconv_kernel<<<144, 256, 0, stream>>>(pw, Wb);
    attn_kernel<<<dim3(256, 8), 256, 0, stream>>>(Qs, Ks, Vs, AOs);
    proj_kernel<<<512, 256, 0, stream>>>(AOs, Wb, pb, out);
}